// Round 6
// baseline (291.665 us; speedup 1.0000x reference)
//
#include <hip/hip_runtime.h>
#include <hip/hip_bf16.h>
#include <stdint.h>

// Conv4d B=1 IC=16 OC=32 K=3^4 pad=1 stride=1, D=32 -> implicit GEMM on MFMA.
// Round 9: quarter-ring LDS. The 96-row x-tile splits into 4 a-row quarters
// (24 rows = 13312 B incl pad); each wave's cstep reads exactly ONE quarter
// (q = ai+da). 3 physical buffers (sA,sB,sC) rotate through 8 quarter-stages
// (Q0..Q3 for g=0, Q0'..Q3' for g=1). LDS 39936 B -> 4 blocks/CU (16 waves,
// was 2.2 blocks measured) for stall coverage. One exposed 13 KB stage at the
// g-boundary (hidden by co-resident blocks). g=1 csteps run da=2,1,0 so the
// ring closes; af prefetch follows execution order.
// Ledger (slot: quarter, staged-during, drained-at, readers):
//   sA: Q0(prologue,B0; c00) -> Q3(c01,B2; c02)  -> Q1'(c12,B5; c11,c10)
//   sB: Q1(prologue,B0; c00,c01) -> Q2'(c02,B3; c12,c11)
//   sC: Q2(prologue,B0; c01,c02) -> Q3'(exposed,B4; c12) -> Q0'(c11,B6; c10)
// Every stage targets a buffer whose last reader preceded the prior barrier;
// every read follows the barrier that drains its stage. All waits are
// __syncthreads(). Compute body, pair-aliased B-frags, verified C/D layout
// identical to round 7/8. pack_xw identical to round 8 (verified).

typedef __bf16 bf16x8 __attribute__((ext_vector_type(8)));
typedef float f32x16 __attribute__((ext_vector_type(16)));

#define X_IC_STRIDE 1048576  // 32^4 elements per ic plane
#define W_K 1296             // 16 * 81
#define WPACK_DWORDS 23040   // 90 frags * 256 dwords (92160 B)
#define XPACK_OFF 98304      // xpack starts here in d_ws (after wpack)
#define XPACK_BYTES 33554432u // 2^20 points * 32 B ([point][g][16B])
#define ZOFF XPACK_BYTES      // 32 B zero page right after xpack
#define Q_SLOTS 816           // 24 rows * 34 pts per quarter
#define Q_BYTES 13312         // 832 slots * 16 B (16-slot stage pad)
#define LEGACY_LDS 52224      // legacy fallback kernel

__device__ __forceinline__ unsigned rne_bf16(float f) {
    unsigned b = __builtin_bit_cast(unsigned, f);
    return (b + 0x7FFFu + ((b >> 16) & 1u)) >> 16;
}

__device__ __forceinline__ void gload_lds16(const unsigned char* g, unsigned char* s) {
    __builtin_amdgcn_global_load_lds(
        (const __attribute__((address_space(1))) unsigned int*)g,
        (__attribute__((address_space(3))) unsigned int*)s, 16, 0, 0);
}

__device__ __forceinline__ void fence_sched() { __builtin_amdgcn_sched_barrier(0); }

// w-pack body. frag fi = (g*9 + dadb)*5 + p ; lane(kh*32+oc)*16B + icpair*4B.
// slot = 2p+kh ; slot 9 = zero pad.
__device__ __forceinline__ void pack_w_body(int D, const float* __restrict__ w,
                                            unsigned* __restrict__ wpack) {
    if (D >= WPACK_DWORDS) return;
    int t    = D & 3;          // ic pair
    int lane = (D >> 2) & 63;
    int fi   = D >> 8;
    int p    = fi % 5;
    int dadb = (fi / 5) % 9;
    int g    = fi / 45;
    int kh   = lane >> 5;
    int oc   = lane & 31;
    int slot = 2 * p + kh;
    unsigned pk = 0u;
    if (slot < 9) {
        int da = dadb / 3, db = dadb % 3;
        int dc = slot / 3, dd = slot % 3;
        int koff = da * 27 + db * 9 + dc * 3 + dd;
        int ic0  = g * 8 + 2 * t;
        unsigned lo = rne_bf16(w[oc * W_K + ic0 * 81 + koff]);
        unsigned hi = rne_bf16(w[oc * W_K + (ic0 + 1) * 81 + koff]);
        pk = lo | (hi << 16);
    }
    wpack[D] = pk;
}

__global__ void pack_w_kernel(const float* __restrict__ w, unsigned* __restrict__ wpack) {
    pack_w_body(blockIdx.x * 256 + threadIdx.x, w, wpack);
}

// Fused pack: x fp32 [16][2^20] -> xpack bf16 [2^20][2 g][16 B] (+zero page),
// and (first 90 blocks) w -> wpack. 2 points per thread, float2 plane loads.
__global__ __launch_bounds__(256) void pack_xw_kernel(const float* __restrict__ x,
                                                      const float* __restrict__ w,
                                                      unsigned char* __restrict__ xpack,
                                                      unsigned* __restrict__ wpack) {
    const int bid = blockIdx.x;          // grid = 2048
    const int tid = threadIdx.x;
    if (bid < (WPACK_DWORDS + 255) / 256)
        pack_w_body(bid * 256 + tid, w, wpack);

    const unsigned P0 = (unsigned)(bid * 256 + tid) * 2u;   // 2 pts/thread
    float2 v[16];
#pragma unroll
    for (int ic = 0; ic < 16; ++ic)
        v[ic] = *(const float2*)(x + (size_t)ic * X_IC_STRIDE + P0);

    uint4 o[4];
#pragma unroll
    for (int pt = 0; pt < 2; ++pt) {
        unsigned u[16];
#pragma unroll
        for (int ic = 0; ic < 16; ++ic)
            u[ic] = rne_bf16(pt ? v[ic].y : v[ic].x);
        o[pt * 2]     = make_uint4(u[0] | (u[1] << 16),  u[2] | (u[3] << 16),
                                   u[4] | (u[5] << 16),  u[6] | (u[7] << 16));
        o[pt * 2 + 1] = make_uint4(u[8] | (u[9] << 16),  u[10] | (u[11] << 16),
                                   u[12] | (u[13] << 16), u[14] | (u[15] << 16));
    }
#pragma unroll
    for (int j = 0; j < 4; ++j)
        *(uint4*)(xpack + (size_t)P0 * 32 + j * 16) = o[j];

    if (P0 == 0) {   // zero page for out-of-range halo points
        *(uint4*)(xpack + ZOFF) = make_uint4(0u, 0u, 0u, 0u);
        *(uint4*)(xpack + ZOFF + 16) = make_uint4(0u, 0u, 0u, 0u);
    }
}

__global__ __launch_bounds__(256, 4) void conv4d_ring(
    const unsigned char* __restrict__ wpack,
    const unsigned char* __restrict__ xpack,
    const float* __restrict__ bias,      // [32]
    float* __restrict__ out)             // [32][32][32][32][32]
{
    // 3-slot quarter ring; distinct arrays so alias analysis separates
    // staging writes from compute reads. (f6[5] reads for the zero-weight
    // pad tap may overrun a quarter by <=288 B into the neighbor / past the
    // last array: garbage * 0-weight, same benign pattern as verified r7.)
    __shared__ __attribute__((aligned(16))) unsigned char sA[Q_BYTES];
    __shared__ __attribute__((aligned(16))) unsigned char sB[Q_BYTES];
    __shared__ __attribute__((aligned(16))) unsigned char sC[Q_BYTES];

    const int tid  = threadIdx.x;
    const int lane = tid & 63;
    const int wv   = tid >> 6;     // wave 0..3
    const int kh   = lane >> 5;    // k-half -> slot select
    const int ln   = lane & 31;    // A: oc ; B: d

    // XCD-aware bijective swizzle (2048 blocks % 8 XCDs == 0).
    const int bid = blockIdx.x;
    const int blk = ((bid & 7) << 8) | (bid >> 3);
    const int c0  = (blk & 7) * 4;
    const int b0  = ((blk >> 3) & 15) * 2;
    const int a0  = (blk >> 7) * 2;
    const int ai  = wv >> 1, bi = wv & 1;

    // per-lane b-frag bases for p=0..2 (pair alias: pbase[p+3]=pbase[p]+1088;
    // the only unpaired case kh=1,p=4 is the zero-weight pad slot, af==0).
    int pbase[3];
#pragma unroll
    for (int p = 0; p < 3; ++p) {
        int slot = 2 * p + kh;
        int dc = slot / 3, dd = slot % 3;
        pbase[p] = dc * 544 + (ln + dd) * 16;
    }

    // Staging: quarter q = a-row group (24 rows x 34 pts = 816 slots).
    // Waves 0-2: 4 full-exec loads (slots wv*256 .. +255); wave 3: 1 load
    // (slots 768..831; 816..831 overflow -> zero page into in-array pad).
    unsigned xoffQ[4][4];
#pragma unroll
    for (int q = 0; q < 4; ++q)
#pragma unroll
        for (int i = 0; i < 4; ++i) {
            int s   = wv * 256 + i * 64 + lane;
            int r24 = s / 34;                 // row within quarter
            int dpr = s % 34;
            int rb = r24 / 6, rc = r24 % 6;
            int a_in = a0 + q - 1, b_in = b0 + rb - 1;
            int c_in = c0 + rc - 1, d_in = dpr - 1;
            bool v = (s < Q_SLOTS) &
                     ((unsigned)a_in < 32u) & ((unsigned)b_in < 32u) &
                     ((unsigned)c_in < 32u) & ((unsigned)d_in < 32u);
            unsigned P = (unsigned)(((a_in * 32 + b_in) * 32 + c_in) * 32 + d_in);
            xoffQ[q][i] = v ? P * 32u : ZOFF;
        }

    f32x16 acc[4];
#pragma unroll
    for (int ci = 0; ci < 4; ++ci)
#pragma unroll
        for (int r = 0; r < 16; ++r) acc[ci][r] = 0.f;

    bf16x8 af[5];

    // stage one quarter for ic-group g (13 gload_lds block-wide: 4/4/4/1)
    auto stage_q = [&](unsigned char* dst, int q, int g) {
        const unsigned gofs = (unsigned)(g << 4);
        unsigned char* base = dst + (wv << 12);   // wv*256 slots *16 B
#pragma unroll
        for (int i = 0; i < 4; ++i) {
            if (i == 0 || wv < 3)   // wave-uniform load counts {4,4,4,1}
                gload_lds16(xpack + xoffQ[q][i] + gofs, base + (i << 10));
        }
    };

    // compute step: wave reads ONLY its quarter (q = ai+da) from `qb`.
    // fiBase = g*9 + da*3 ; nextBase = first fi of the NEXT executed cstep.
    auto cstep = [&](const unsigned char* qb, int fiBase, int nextBase) {
#pragma unroll
        for (int db = 0; db < 3; ++db) {
            const int fi  = fiBase + db;
            const int nfi = (db < 2) ? fi + 1 : nextBase;
            bf16x8 afn[5];
#pragma unroll
            for (int p = 0; p < 5; ++p)
                afn[p] = *(const bf16x8*)(wpack + ((size_t)nfi * 5 + p) * 1024 + lane * 16);

            const unsigned char* rbase = qb + (bi + db) * 3264;   // (bi+db)*6*544
            __builtin_amdgcn_s_setprio(1);
#pragma unroll
            for (int p = 0; p < 2; ++p) {
                const unsigned char* bp = rbase + pbase[p];
                bf16x8 f6[6];
#pragma unroll
                for (int j = 0; j < 6; ++j)
                    f6[j] = *(const bf16x8*)(bp + j * 544);
#pragma unroll
                for (int ci = 0; ci < 4; ++ci)
                    acc[ci] = __builtin_amdgcn_mfma_f32_32x32x16_bf16(
                        af[p], f6[ci], acc[ci], 0, 0, 0);
#pragma unroll
                for (int ci = 0; ci < 4; ++ci)
                    acc[ci] = __builtin_amdgcn_mfma_f32_32x32x16_bf16(
                        af[p + 3], f6[ci + 2], acc[ci], 0, 0, 0);
            }
            {
                const unsigned char* bp = rbase + pbase[2];
#pragma unroll
                for (int ci = 0; ci < 4; ++ci) {
                    bf16x8 bfrag = *(const bf16x8*)(bp + ci * 544);
                    acc[ci] = __builtin_amdgcn_mfma_f32_32x32x16_bf16(
                        af[2], bfrag, acc[ci], 0, 0, 0);
                }
            }
            __builtin_amdgcn_s_setprio(0);
#pragma unroll
            for (int p = 0; p < 5; ++p) af[p] = afn[p];
        }
    };

    // ---------------- ring schedule (all waits = __syncthreads) ----------
    stage_q(sA, 0, 0);          // Q0
    stage_q(sB, 1, 0);          // Q1
    stage_q(sC, 2, 0);          // Q2
#pragma unroll
    for (int p = 0; p < 5; ++p)
        af[p] = *(const bf16x8*)(wpack + (size_t)p * 1024 + lane * 16);
    __syncthreads();            // B0: Q0,Q1,Q2 ready

    cstep(ai ? sB : sA, 0, 3);  // c00: q=ai
    __syncthreads();            // B1: Q0 dead
    stage_q(sA, 3, 0);          // Q3 -> sA (drains under c01)
    fence_sched();
    cstep(ai ? sC : sB, 3, 6);  // c01: q=ai+1
    __syncthreads();            // B2: drains Q3; Q1 dead
    stage_q(sB, 2, 1);          // Q2' -> sB (drains under c02)
    fence_sched();
    cstep(ai ? sA : sC, 6, 15); // c02: q=ai+2 (slot (ai+2)%3)
    __syncthreads();            // B3: drains Q2'; Q2,Q3 dead
    stage_q(sC, 3, 1);          // Q3' -> sC
    __syncthreads();            // B4: drains Q3' [the one exposed stage]
    stage_q(sA, 1, 1);          // Q1' -> sA (drains under c12)
    fence_sched();
    cstep(ai ? sC : sB, 15, 12);// c12: q=ai+2, slot (ai+4)%3
    __syncthreads();            // B5: drains Q1'
    stage_q(sC, 0, 1);          // Q0' -> sC (drains under c11)
    fence_sched();
    cstep(ai ? sB : sA, 12, 9); // c11: q=ai+1, slot (ai+3)%3
    __syncthreads();            // B6: drains Q0'
    cstep(ai ? sA : sC, 9, 0);  // c10: q=ai, slot (ai+2)%3

    // epilogue: D col = lane&31 = d (coalesced), row oc = (r&3)+8*(r>>2)+4*kh
    float bv[16];
#pragma unroll
    for (int r = 0; r < 16; ++r) bv[r] = bias[(r & 3) + 8 * (r >> 2) + 4 * kh];

    const size_t sp_base = (((size_t)(a0 + ai) * 32 + (b0 + bi)) * 32 + c0);
#pragma unroll
    for (int ci = 0; ci < 4; ++ci) {
#pragma unroll
        for (int r = 0; r < 16; ++r) {
            int oc_ = (r & 3) + 8 * (r >> 2) + 4 * kh;
            out[(size_t)oc_ * X_IC_STRIDE + (sp_base + ci) * 32 + ln] = acc[ci][r] + bv[r];
        }
    }
}

// Legacy fallback (ws too small for xpack): on-the-fly cvt staging.
__global__ __launch_bounds__(256, 3) void conv4d_legacy(
    const float* __restrict__ x,
    const unsigned char* __restrict__ wpack,
    const float* __restrict__ bias,
    float* __restrict__ out)
{
    __shared__ __attribute__((aligned(16))) unsigned char lds[LEGACY_LDS];

    const int tid  = threadIdx.x;
    const int lane = tid & 63;
    const int wv   = tid >> 6;
    const int kh   = lane >> 5;
    const int ln   = lane & 31;

    const int bid = blockIdx.x;
    const int blk = ((bid & 7) << 8) | (bid >> 3);
    const int c0  = (blk & 7) * 4;
    const int b0  = ((blk >> 3) & 15) * 2;
    const int a0  = (blk >> 7) * 2;
    const int ai  = wv >> 1, bi = wv & 1;

    int pbase[3];
#pragma unroll
    for (int p = 0; p < 3; ++p) {
        int slot = 2 * p + kh;
        int dc = slot / 3, dd = slot % 3;
        pbase[p] = dc * 544 + (ln + dd) * 16;
    }

    f32x16 acc[4];
#pragma unroll
    for (int ci = 0; ci < 4; ++ci)
#pragma unroll
        for (int r = 0; r < 16; ++r) acc[ci][r] = 0.f;

    bf16x8 af[5];
#pragma unroll
    for (int p = 0; p < 5; ++p)
        af[p] = *(const bf16x8*)(wpack + (size_t)p * 1024 + lane * 16);

    for (int g = 0; g < 2; ++g) {
        if (g) __syncthreads();
        for (int t = tid; t < 96 * 34; t += 256) {
            int dpr = t % 34;
            int row = t / 34;
            int rc = row % 6; int r2 = row / 6;
            int rb = r2 & 3;  int ra = r2 >> 2;
            int a_in = a0 + ra - 1, b_in = b0 + rb - 1;
            int c_in = c0 + rc - 1, d_in = dpr - 1;
            uint4 pk = make_uint4(0u, 0u, 0u, 0u);
            if ((unsigned)a_in < 32u && (unsigned)b_in < 32u &&
                (unsigned)c_in < 32u && (unsigned)d_in < 32u) {
                const float* xp = x + (size_t)(g * 8) * X_IC_STRIDE +
                                  (((a_in * 32 + b_in) * 32 + c_in) * 32 + d_in);
                unsigned u[8];
#pragma unroll
                for (int j = 0; j < 8; ++j)
                    u[j] = rne_bf16(xp[j * X_IC_STRIDE]);
                pk.x = u[0] | (u[1] << 16); pk.y = u[2] | (u[3] << 16);
                pk.z = u[4] | (u[5] << 16); pk.w = u[6] | (u[7] << 16);
            }
            *(uint4*)(lds + t * 16) = pk;
        }
        __syncthreads();

        for (int dadb = 0; dadb < 9; ++dadb) {
            const int fi  = g * 9 + dadb;
            const int nfi = (fi + 1 > 17) ? 17 : fi + 1;
            bf16x8 afn[5];
#pragma unroll
            for (int p = 0; p < 5; ++p)
                afn[p] = *(const bf16x8*)(wpack + ((size_t)nfi * 5 + p) * 1024 + lane * 16);

            const int da = dadb / 3, db = dadb % 3;
            const int ubase = ((ai + da) * 24 + (bi + db) * 6) * 544;
#pragma unroll
            for (int p = 0; p < 2; ++p) {
                const unsigned char* bp = lds + ubase + pbase[p];
                bf16x8 f6[6];
#pragma unroll
                for (int j = 0; j < 6; ++j)
                    f6[j] = *(const bf16x8*)(bp + j * 544);
#pragma unroll
                for (int ci = 0; ci < 4; ++ci)
                    acc[ci] = __builtin_amdgcn_mfma_f32_32x32x16_bf16(
                        af[p], f6[ci], acc[ci], 0, 0, 0);
#pragma unroll
                for (int ci = 0; ci < 4; ++ci)
                    acc[ci] = __builtin_amdgcn_mfma_f32_32x32x16_bf16(
                        af[p + 3], f6[ci + 2], acc[ci], 0, 0, 0);
            }
            {
                const unsigned char* bp = lds + ubase + pbase[2];
#pragma unroll
                for (int ci = 0; ci < 4; ++ci) {
                    bf16x8 bfrag = *(const bf16x8*)(bp + ci * 544);
                    acc[ci] = __builtin_amdgcn_mfma_f32_32x32x16_bf16(
                        af[2], bfrag, acc[ci], 0, 0, 0);
                }
            }
#pragma unroll
            for (int p = 0; p < 5; ++p) af[p] = afn[p];
        }
    }

    float bv[16];
#pragma unroll
    for (int r = 0; r < 16; ++r) bv[r] = bias[(r & 3) + 8 * (r >> 2) + 4 * kh];

    const size_t sp_base = (((size_t)(a0 + ai) * 32 + (b0 + bi)) * 32 + c0);
#pragma unroll
    for (int ci = 0; ci < 4; ++ci) {
#pragma unroll
        for (int r = 0; r < 16; ++r) {
            int oc_ = (r & 3) + 8 * (r >> 2) + 4 * kh;
            out[(size_t)oc_ * X_IC_STRIDE + (sp_base + ci) * 32 + ln] = acc[ci][r] + bv[r];
        }
    }
}

extern "C" void kernel_launch(void* const* d_in, const int* in_sizes, int n_in,
                              void* d_out, int out_size, void* d_ws, size_t ws_size,
                              hipStream_t stream) {
    const float* x    = (const float*)d_in[0];
    const float* w    = (const float*)d_in[1];
    const float* bias = (const float*)d_in[2];
    float* out        = (float*)d_out;
    unsigned* wpack   = (unsigned*)d_ws;                       // 92160 B
    unsigned char* xpack = (unsigned char*)d_ws + XPACK_OFF;   // 32 MiB + 32 B

    if (ws_size >= (size_t)XPACK_OFF + XPACK_BYTES + 32) {
        pack_xw_kernel<<<dim3(2048), dim3(256), 0, stream>>>(x, w, xpack, wpack);
        conv4d_ring<<<dim3(2048), dim3(256), 0, stream>>>(
            (const unsigned char*)d_ws, xpack, bias, out);
    } else {
        pack_w_kernel<<<dim3((WPACK_DWORDS + 255) / 256), dim3(256), 0, stream>>>(w, wpack);
        conv4d_legacy<<<dim3(2048), dim3(256), 0, stream>>>(
            x, (const unsigned char*)d_ws, bias, out);
    }
}

// Round 8
// 257.969 us; speedup vs baseline: 1.1306x; 1.1306x over previous
//
#include <hip/hip_runtime.h>
#include <hip/hip_bf16.h>
#include <stdint.h>

// Conv4d B=1 IC=16 OC=32 K=3^4 pad=1 stride=1, D=32 -> implicit GEMM on MFMA.
// Round 11: quarter-ring LDS, overrun-pad fixed.
// Root cause of r9/r10 NaN: pair-aliased f6 tail reads reach
// rbase(<=9792) + pbase[1]|kh=1(<=1040) + 5*544+16 = 13568 B, i.e. 256 B past
// the 13312 B a stage writes. Those bytes were NEVER written -> uninit LDS;
// NaN bit-pattern * 0-weight = NaN. (r7 pipe was safe because its per-half
// pad WAS staged every time.) Fix: Q_BYTES=13568 and a one-time zero-fill of
// bytes 13312..13568 of each buffer before the first barrier (stages never
// touch them; only zero-weight taps read them).
// Also kept from r10 (untested due to the NaN): __launch_bounds__(256,3)
// (r9's (256,4) forced VGPR=64 -> acc spills, FETCH+58/WRITE+92 MB) and the
// staging-offset register diet (a_in*1MiB + bro[(b,c,d)], bit-identical).
// Ring ledger (audited, no WAR races; all waits __syncthreads):
//   sA: Q0(prologue,B0; c00) -> Q3(c01,B2; c02)  -> Q1'(c12,B5; c11,c10)
//   sB: Q1(prologue,B0; c00,c01) -> Q2'(c02,B3; c12,c11)
//   sC: Q2(prologue,B0; c01,c02) -> Q3'(exposed,B4; c12) -> Q0'(c11,B6; c10)
// LDS 3*13568 = 40704 B -> 4 blocks/CU (162816 <= 163840).
// Compute body, pair-aliased B-frags, verified C/D layout = r7/r8 (passed).

typedef __bf16 bf16x8 __attribute__((ext_vector_type(8)));
typedef float f32x16 __attribute__((ext_vector_type(16)));

#define X_IC_STRIDE 1048576  // 32^4 elements per ic plane
#define W_K 1296             // 16 * 81
#define WPACK_DWORDS 23040   // 90 frags * 256 dwords (92160 B)
#define XPACK_OFF 98304      // xpack starts here in d_ws (after wpack)
#define XPACK_BYTES 33554432u // 2^20 points * 32 B ([point][g][16B])
#define ZOFF XPACK_BYTES      // 32 B zero page right after xpack
#define Q_SLOTS 816           // 24 rows * 34 pts per quarter
#define Q_STAGE_B 13312       // bytes written per stage (832 slots)
#define Q_BYTES 13568         // + 256 B read-overrun pad (zero-filled once)
#define A_STRIDE_B 1048576u   // a-dim contribution to xpack byte offset
#define LEGACY_LDS 52224      // legacy fallback kernel

__device__ __forceinline__ unsigned rne_bf16(float f) {
    unsigned b = __builtin_bit_cast(unsigned, f);
    return (b + 0x7FFFu + ((b >> 16) & 1u)) >> 16;
}

__device__ __forceinline__ void gload_lds16(const unsigned char* g, unsigned char* s) {
    __builtin_amdgcn_global_load_lds(
        (const __attribute__((address_space(1))) unsigned int*)g,
        (__attribute__((address_space(3))) unsigned int*)s, 16, 0, 0);
}

__device__ __forceinline__ void fence_sched() { __builtin_amdgcn_sched_barrier(0); }

// w-pack body. frag fi = (g*9 + dadb)*5 + p ; lane(kh*32+oc)*16B + icpair*4B.
// slot = 2p+kh ; slot 9 = zero pad.
__device__ __forceinline__ void pack_w_body(int D, const float* __restrict__ w,
                                            unsigned* __restrict__ wpack) {
    if (D >= WPACK_DWORDS) return;
    int t    = D & 3;          // ic pair
    int lane = (D >> 2) & 63;
    int fi   = D >> 8;
    int p    = fi % 5;
    int dadb = (fi / 5) % 9;
    int g    = fi / 45;
    int kh   = lane >> 5;
    int oc   = lane & 31;
    int slot = 2 * p + kh;
    unsigned pk = 0u;
    if (slot < 9) {
        int da = dadb / 3, db = dadb % 3;
        int dc = slot / 3, dd = slot % 3;
        int koff = da * 27 + db * 9 + dc * 3 + dd;
        int ic0  = g * 8 + 2 * t;
        unsigned lo = rne_bf16(w[oc * W_K + ic0 * 81 + koff]);
        unsigned hi = rne_bf16(w[oc * W_K + (ic0 + 1) * 81 + koff]);
        pk = lo | (hi << 16);
    }
    wpack[D] = pk;
}

__global__ void pack_w_kernel(const float* __restrict__ w, unsigned* __restrict__ wpack) {
    pack_w_body(blockIdx.x * 256 + threadIdx.x, w, wpack);
}

// Fused pack: x fp32 [16][2^20] -> xpack bf16 [2^20][2 g][16 B] (+zero page),
// and (first 90 blocks) w -> wpack. 2 points per thread, float2 plane loads.
__global__ __launch_bounds__(256) void pack_xw_kernel(const float* __restrict__ x,
                                                      const float* __restrict__ w,
                                                      unsigned char* __restrict__ xpack,
                                                      unsigned* __restrict__ wpack) {
    const int bid = blockIdx.x;          // grid = 2048
    const int tid = threadIdx.x;
    if (bid < (WPACK_DWORDS + 255) / 256)
        pack_w_body(bid * 256 + tid, w, wpack);

    const unsigned P0 = (unsigned)(bid * 256 + tid) * 2u;   // 2 pts/thread
    float2 v[16];
#pragma unroll
    for (int ic = 0; ic < 16; ++ic)
        v[ic] = *(const float2*)(x + (size_t)ic * X_IC_STRIDE + P0);

    uint4 o[4];
#pragma unroll
    for (int pt = 0; pt < 2; ++pt) {
        unsigned u[16];
#pragma unroll
        for (int ic = 0; ic < 16; ++ic)
            u[ic] = rne_bf16(pt ? v[ic].y : v[ic].x);
        o[pt * 2]     = make_uint4(u[0] | (u[1] << 16),  u[2] | (u[3] << 16),
                                   u[4] | (u[5] << 16),  u[6] | (u[7] << 16));
        o[pt * 2 + 1] = make_uint4(u[8] | (u[9] << 16),  u[10] | (u[11] << 16),
                                   u[12] | (u[13] << 16), u[14] | (u[15] << 16));
    }
#pragma unroll
    for (int j = 0; j < 4; ++j)
        *(uint4*)(xpack + (size_t)P0 * 32 + j * 16) = o[j];

    if (P0 == 0) {   // zero page for out-of-range halo points
        *(uint4*)(xpack + ZOFF) = make_uint4(0u, 0u, 0u, 0u);
        *(uint4*)(xpack + ZOFF + 16) = make_uint4(0u, 0u, 0u, 0u);
    }
}

__global__ __launch_bounds__(256, 3) void conv4d_ring(
    const unsigned char* __restrict__ wpack,
    const unsigned char* __restrict__ xpack,
    const float* __restrict__ bias,      // [32]
    float* __restrict__ out)             // [32][32][32][32][32]
{
    // 3-slot quarter ring; distinct arrays so alias analysis separates
    // staging writes from compute reads. Each buffer: 13312 B staged data
    // + 256 B zero-filled pad (read only by zero-weight taps, kh=1 lanes).
    __shared__ __attribute__((aligned(16))) unsigned char sA[Q_BYTES];
    __shared__ __attribute__((aligned(16))) unsigned char sB[Q_BYTES];
    __shared__ __attribute__((aligned(16))) unsigned char sC[Q_BYTES];

    const int tid  = threadIdx.x;
    const int lane = tid & 63;
    const int wv   = tid >> 6;     // wave 0..3
    const int kh   = lane >> 5;    // k-half -> slot select
    const int ln   = lane & 31;    // A: oc ; B: d

    // XCD-aware bijective swizzle (2048 blocks % 8 XCDs == 0).
    const int bid = blockIdx.x;
    const int blk = ((bid & 7) << 8) | (bid >> 3);
    const int c0  = (blk & 7) * 4;
    const int b0  = ((blk >> 3) & 15) * 2;
    const int a0  = (blk >> 7) * 2;
    const int ai  = wv >> 1, bi = wv & 1;

    // One-time zero-fill of each buffer's read-overrun pad (bytes
    // 13312..13568). Stages never write these; only zero-weight taps read
    // them -> any finite value is correct; fill before the first barrier.
    if (tid < 48) {
        int arr = tid >> 4, j = tid & 15;
        unsigned char* base = (arr == 0) ? sA : (arr == 1) ? sB : sC;
        *(uint4*)(base + Q_STAGE_B + j * 16) = make_uint4(0u, 0u, 0u, 0u);
    }

    // per-lane b-frag bases for p=0..2 (pair alias: pbase[p+3]=pbase[p]+1088;
    // the only unpaired case kh=1,p=4 is the zero-weight pad slot, af==0).
    int pbase[3];
#pragma unroll
    for (int p = 0; p < 3; ++p) {
        int slot = 2 * p + kh;
        int dc = slot / 3, dd = slot % 3;
        pbase[p] = dc * 544 + (ln + dd) * 16;
    }

    // Staging (register diet): the a-dim adds a pure a_in*1MiB byte offset,
    // so keep only the (b,c,d) part bro[i] + validity. Waves 0-2: 4
    // full-exec loads (slots wv*256..+255); wave 3: 1 load (768..831;
    // 816+ overflow -> zero page into the staged in-array pad).
    unsigned bro[4];
    bool     vbcd[4];
#pragma unroll
    for (int i = 0; i < 4; ++i) {
        int s   = wv * 256 + i * 64 + lane;
        int r24 = s / 34;                 // row within quarter
        int dpr = s % 34;
        int rb = r24 / 6, rc = r24 % 6;
        int b_in = b0 + rb - 1;
        int c_in = c0 + rc - 1;
        int d_in = dpr - 1;
        vbcd[i] = (s < Q_SLOTS) &
                  ((unsigned)b_in < 32u) & ((unsigned)c_in < 32u) &
                  ((unsigned)d_in < 32u);
        bro[i]  = (unsigned)(((b_in * 32 + c_in) * 32 + d_in) * 32);
    }

    f32x16 acc[4];
#pragma unroll
    for (int ci = 0; ci < 4; ++ci)
#pragma unroll
        for (int r = 0; r < 16; ++r) acc[ci][r] = 0.f;

    bf16x8 af[5];

    // stage one quarter for ic-group g (13 gload_lds block-wide: 4/4/4/1)
    auto stage_q = [&](unsigned char* dst, int q, int g) {
        const unsigned gofs = (unsigned)(g << 4);
        const unsigned a_in = (unsigned)(a0 + q - 1);
        const bool     aok  = a_in < 32u;
        const unsigned abase = a_in * A_STRIDE_B;
        unsigned char* base = dst + (wv << 12);   // wv*256 slots *16 B
#pragma unroll
        for (int i = 0; i < 4; ++i) {
            if (i == 0 || wv < 3) {  // wave-uniform load counts {4,4,4,1}
                unsigned off = (vbcd[i] & aok) ? abase + bro[i] : ZOFF;
                gload_lds16(xpack + off + gofs, base + (i << 10));
            }
        }
    };

    // compute step: wave reads ONLY its quarter (q = ai+da) from `qb`.
    // fiBase = g*9 + da*3 ; nextBase = first fi of the NEXT executed cstep.
    auto cstep = [&](const unsigned char* qb, int fiBase, int nextBase) {
#pragma unroll
        for (int db = 0; db < 3; ++db) {
            const int fi  = fiBase + db;
            const int nfi = (db < 2) ? fi + 1 : nextBase;
            bf16x8 afn[5];
#pragma unroll
            for (int p = 0; p < 5; ++p)
                afn[p] = *(const bf16x8*)(wpack + ((size_t)nfi * 5 + p) * 1024 + lane * 16);

            const unsigned char* rbase = qb + (bi + db) * 3264;   // (bi+db)*6*544
            __builtin_amdgcn_s_setprio(1);
#pragma unroll
            for (int p = 0; p < 2; ++p) {
                const unsigned char* bp = rbase + pbase[p];
                bf16x8 f6[6];
#pragma unroll
                for (int j = 0; j < 6; ++j)
                    f6[j] = *(const bf16x8*)(bp + j * 544);
#pragma unroll
                for (int ci = 0; ci < 4; ++ci)
                    acc[ci] = __builtin_amdgcn_mfma_f32_32x32x16_bf16(
                        af[p], f6[ci], acc[ci], 0, 0, 0);
#pragma unroll
                for (int ci = 0; ci < 4; ++ci)
                    acc[ci] = __builtin_amdgcn_mfma_f32_32x32x16_bf16(
                        af[p + 3], f6[ci + 2], acc[ci], 0, 0, 0);
            }
            {
                const unsigned char* bp = rbase + pbase[2];
#pragma unroll
                for (int ci = 0; ci < 4; ++ci) {
                    bf16x8 bfrag = *(const bf16x8*)(bp + ci * 544);
                    acc[ci] = __builtin_amdgcn_mfma_f32_32x32x16_bf16(
                        af[2], bfrag, acc[ci], 0, 0, 0);
                }
            }
            __builtin_amdgcn_s_setprio(0);
#pragma unroll
            for (int p = 0; p < 5; ++p) af[p] = afn[p];
        }
    };

    // ---------------- ring schedule (all waits = __syncthreads) ----------
    stage_q(sA, 0, 0);          // Q0
    stage_q(sB, 1, 0);          // Q1
    stage_q(sC, 2, 0);          // Q2
#pragma unroll
    for (int p = 0; p < 5; ++p)
        af[p] = *(const bf16x8*)(wpack + (size_t)p * 1024 + lane * 16);
    __syncthreads();            // B0: Q0,Q1,Q2 (and pad fill) ready

    cstep(ai ? sB : sA, 0, 3);  // c00: q=ai
    __syncthreads();            // B1: Q0 dead
    stage_q(sA, 3, 0);          // Q3 -> sA (drains under c01)
    fence_sched();
    cstep(ai ? sC : sB, 3, 6);  // c01: q=ai+1
    __syncthreads();            // B2: drains Q3; Q1 dead
    stage_q(sB, 2, 1);          // Q2' -> sB (drains under c02)
    fence_sched();
    cstep(ai ? sA : sC, 6, 15); // c02: q=ai+2 (slot (ai+2)%3)
    __syncthreads();            // B3: drains Q2'; Q2,Q3 dead
    stage_q(sC, 3, 1);          // Q3' -> sC
    __syncthreads();            // B4: drains Q3' [the one exposed stage]
    stage_q(sA, 1, 1);          // Q1' -> sA (drains under c12)
    fence_sched();
    cstep(ai ? sC : sB, 15, 12);// c12: q=ai+2, slot (ai+4)%3
    __syncthreads();            // B5: drains Q1'
    stage_q(sC, 0, 1);          // Q0' -> sC (drains under c11)
    fence_sched();
    cstep(ai ? sB : sA, 12, 9); // c11: q=ai+1, slot (ai+3)%3
    __syncthreads();            // B6: drains Q0'
    cstep(ai ? sA : sC, 9, 0);  // c10: q=ai, slot (ai+2)%3

    // epilogue: D col = lane&31 = d (coalesced), row oc = (r&3)+8*(r>>2)+4*kh
    float bv[16];
#pragma unroll
    for (int r = 0; r < 16; ++r) bv[r] = bias[(r & 3) + 8 * (r >> 2) + 4 * kh];

    const size_t sp_base = (((size_t)(a0 + ai) * 32 + (b0 + bi)) * 32 + c0);
#pragma unroll
    for (int ci = 0; ci < 4; ++ci) {
#pragma unroll
        for (int r = 0; r < 16; ++r) {
            int oc_ = (r & 3) + 8 * (r >> 2) + 4 * kh;
            out[(size_t)oc_ * X_IC_STRIDE + (sp_base + ci) * 32 + ln] = acc[ci][r] + bv[r];
        }
    }
}

// Legacy fallback (ws too small for xpack): on-the-fly cvt staging.
__global__ __launch_bounds__(256, 3) void conv4d_legacy(
    const float* __restrict__ x,
    const unsigned char* __restrict__ wpack,
    const float* __restrict__ bias,
    float* __restrict__ out)
{
    __shared__ __attribute__((aligned(16))) unsigned char lds[LEGACY_LDS];

    const int tid  = threadIdx.x;
    const int lane = tid & 63;
    const int wv   = tid >> 6;
    const int kh   = lane >> 5;
    const int ln   = lane & 31;

    const int bid = blockIdx.x;
    const int blk = ((bid & 7) << 8) | (bid >> 3);
    const int c0  = (blk & 7) * 4;
    const int b0  = ((blk >> 3) & 15) * 2;
    const int a0  = (blk >> 7) * 2;
    const int ai  = wv >> 1, bi = wv & 1;

    int pbase[3];
#pragma unroll
    for (int p = 0; p < 3; ++p) {
        int slot = 2 * p + kh;
        int dc = slot / 3, dd = slot % 3;
        pbase[p] = dc * 544 + (ln + dd) * 16;
    }

    f32x16 acc[4];
#pragma unroll
    for (int ci = 0; ci < 4; ++ci)
#pragma unroll
        for (int r = 0; r < 16; ++r) acc[ci][r] = 0.f;

    bf16x8 af[5];
#pragma unroll
    for (int p = 0; p < 5; ++p)
        af[p] = *(const bf16x8*)(wpack + (size_t)p * 1024 + lane * 16);

    for (int g = 0; g < 2; ++g) {
        if (g) __syncthreads();
        for (int t = tid; t < 96 * 34; t += 256) {
            int dpr = t % 34;
            int row = t / 34;
            int rc = row % 6; int r2 = row / 6;
            int rb = r2 & 3;  int ra = r2 >> 2;
            int a_in = a0 + ra - 1, b_in = b0 + rb - 1;
            int c_in = c0 + rc - 1, d_in = dpr - 1;
            uint4 pk = make_uint4(0u, 0u, 0u, 0u);
            if ((unsigned)a_in < 32u && (unsigned)b_in < 32u &&
                (unsigned)c_in < 32u && (unsigned)d_in < 32u) {
                const float* xp = x + (size_t)(g * 8) * X_IC_STRIDE +
                                  (((a_in * 32 + b_in) * 32 + c_in) * 32 + d_in);
                unsigned u[8];
#pragma unroll
                for (int j = 0; j < 8; ++j)
                    u[j] = rne_bf16(xp[j * X_IC_STRIDE]);
                pk.x = u[0] | (u[1] << 16); pk.y = u[2] | (u[3] << 16);
                pk.z = u[4] | (u[5] << 16); pk.w = u[6] | (u[7] << 16);
            }
            *(uint4*)(lds + t * 16) = pk;
        }
        __syncthreads();

        for (int dadb = 0; dadb < 9; ++dadb) {
            const int fi  = g * 9 + dadb;
            const int nfi = (fi + 1 > 17) ? 17 : fi + 1;
            bf16x8 afn[5];
#pragma unroll
            for (int p = 0; p < 5; ++p)
                afn[p] = *(const bf16x8*)(wpack + ((size_t)nfi * 5 + p) * 1024 + lane * 16);

            const int da = dadb / 3, db = dadb % 3;
            const int ubase = ((ai + da) * 24 + (bi + db) * 6) * 544;
#pragma unroll
            for (int p = 0; p < 2; ++p) {
                const unsigned char* bp = lds + ubase + pbase[p];
                bf16x8 f6[6];
#pragma unroll
                for (int j = 0; j < 6; ++j)
                    f6[j] = *(const bf16x8*)(bp + j * 544);
#pragma unroll
                for (int ci = 0; ci < 4; ++ci)
                    acc[ci] = __builtin_amdgcn_mfma_f32_32x32x16_bf16(
                        af[p], f6[ci], acc[ci], 0, 0, 0);
#pragma unroll
                for (int ci = 0; ci < 4; ++ci)
                    acc[ci] = __builtin_amdgcn_mfma_f32_32x32x16_bf16(
                        af[p + 3], f6[ci + 2], acc[ci], 0, 0, 0);
            }
            {
                const unsigned char* bp = lds + ubase + pbase[2];
#pragma unroll
                for (int ci = 0; ci < 4; ++ci) {
                    bf16x8 bfrag = *(const bf16x8*)(bp + ci * 544);
                    acc[ci] = __builtin_amdgcn_mfma_f32_32x32x16_bf16(
                        af[2], bfrag, acc[ci], 0, 0, 0);
                }
            }
#pragma unroll
            for (int p = 0; p < 5; ++p) af[p] = afn[p];
        }
    }

    float bv[16];
#pragma unroll
    for (int r = 0; r < 16; ++r) bv[r] = bias[(r & 3) + 8 * (r >> 2) + 4 * kh];

    const size_t sp_base = (((size_t)(a0 + ai) * 32 + (b0 + bi)) * 32 + c0);
#pragma unroll
    for (int ci = 0; ci < 4; ++ci) {
#pragma unroll
        for (int r = 0; r < 16; ++r) {
            int oc_ = (r & 3) + 8 * (r >> 2) + 4 * kh;
            out[(size_t)oc_ * X_IC_STRIDE + (sp_base + ci) * 32 + ln] = acc[ci][r] + bv[r];
        }
    }
}

extern "C" void kernel_launch(void* const* d_in, const int* in_sizes, int n_in,
                              void* d_out, int out_size, void* d_ws, size_t ws_size,
                              hipStream_t stream) {
    const float* x    = (const float*)d_in[0];
    const float* w    = (const float*)d_in[1];
    const float* bias = (const float*)d_in[2];
    float* out        = (float*)d_out;
    unsigned* wpack   = (unsigned*)d_ws;                       // 92160 B
    unsigned char* xpack = (unsigned char*)d_ws + XPACK_OFF;   // 32 MiB + 32 B

    if (ws_size >= (size_t)XPACK_OFF + XPACK_BYTES + 32) {
        pack_xw_kernel<<<dim3(2048), dim3(256), 0, stream>>>(x, w, xpack, wpack);
        conv4d_ring<<<dim3(2048), dim3(256), 0, stream>>>(
            (const unsigned char*)d_ws, xpack, bias, out);
    } else {
        pack_w_kernel<<<dim3((WPACK_DWORDS + 255) / 256), dim3(256), 0, stream>>>(w, wpack);
        conv4d_legacy<<<dim3(2048), dim3(256), 0, stream>>>(
            x, (const unsigned char*)d_ws, bias, out);
    }
}